// Round 8
// baseline (1462.143 us; speedup 1.0000x reference)
//
#include <hip/hip_runtime.h>
#include <hip/hip_bf16.h>
#include <math.h>

#define BB 256      // batch
#define TT 96       // seq len
#define PP 96       // pred len
#define CC 321      // enc_in
#define CP 352      // padded enc_in (11*32)
#define DD 512      // d_model
#define GG 2048     // 4*DD
#define NSTEPS 191  // 96 encoder + 95 decoder (decoder step 96 output is unused)
#define HROT ((size_t)BB * DD)   // elements per h row (one step)

typedef __attribute__((ext_vector_type(8))) short bf16x8;
typedef __attribute__((ext_vector_type(4))) float f32x4;
typedef __hip_bfloat16 bf16;
typedef unsigned long long u64;

// ---------------------------------------------------------------------------
// Instance norm over time: mean/stdev per (b,c); write normalized x to
// xnorm[t][b][c] (bf16, row pitch CP, pad cols pre-zeroed by memset).
__global__ void norm_kernel(const float* __restrict__ x, float* __restrict__ meanp,
                            float* __restrict__ stdp, bf16* __restrict__ xn) {
    int g = blockIdx.x * 256 + threadIdx.x;      // 0 .. BB*CC-1
    if (g >= BB * CC) return;
    int b = g / CC, c = g % CC;
    const float* xp = x + b * TT * CC + c;
    float s = 0.f;
    for (int t = 0; t < TT; ++t) s += xp[t * CC];
    float mu = s * (1.f / TT);
    float v = 0.f;
    for (int t = 0; t < TT; ++t) { float d0 = xp[t * CC] - mu; v += d0 * d0; }
    float sd = sqrtf(v * (1.f / TT) + 1e-5f);
    float rs = 1.f / sd;
    meanp[g] = mu;
    stdp[g] = sd;
    for (int t = 0; t < TT; ++t)
        xn[(t * BB + b) * CP + c] = __float2bfloat16((xp[t * CC] - mu) * rs);
}

// Cast fp32 [rows][cols] -> bf16 [rows][ldd] (pad cols pre-zeroed if ldd>cols)
__global__ void cast_pad_kernel(const float* __restrict__ src, bf16* __restrict__ dst,
                                int rows, int cols, int ldd) {
    int i = blockIdx.x * 256 + threadIdx.x;
    if (i >= rows * cols) return;
    int r = i / cols, c = i % cols;
    dst[r * ldd + c] = __float2bfloat16(src[i]);
}

// WpT[d][c] = Wp[c][d]  (bf16, row pitch CP, pad pre-zeroed)
__global__ void transpose_wp_kernel(const float* __restrict__ wp, bf16* __restrict__ wpt) {
    int i = blockIdx.x * 256 + threadIdx.x;      // over DD*CC
    if (i >= DD * CC) return;
    int d = i / CC, c = i % CC;
    wpt[d * CP + c] = __float2bfloat16(wp[c * DD + d]);
}

// bsum[j] = bih+bhh ; beff[j] = bih+bhh + dot(Wih[j,:], bp)   (fp32)
__global__ void bias_kernel(const float* __restrict__ Wih, const float* __restrict__ bih,
                            const float* __restrict__ bhh, const float* __restrict__ bp,
                            float* __restrict__ bsum, float* __restrict__ beff) {
    int j = blockIdx.x * 256 + threadIdx.x;      // 2048
    if (j >= GG) return;
    float s = bih[j] + bhh[j];
    float acc = 0.f;
    const float* w = Wih + j * CC;
    for (int c = 0; c < CC; ++c) acc += w[c] * bp[c];
    bsum[j] = s;
    beff[j] = s + acc;
}

// ---------------------------------------------------------------------------
// Generic 64x64 block MFMA core: C[m][n] = sum_k A[m][k] * Bt[n][k]
__device__ __forceinline__ void gemm_core_64x64(const bf16* A, int lda, const bf16* Bt,
                                                int ldb, int K, int m0, int n0,
                                                f32x4 acc[4]) {
    __shared__ unsigned short As[64][40];
    __shared__ unsigned short Bs[64][40];
    int tid = threadIdx.x;
    int w = tid >> 6, lane = tid & 63;
    int quad = lane >> 4, col = lane & 15;
    int lr = tid >> 2, lc = (tid & 3) * 8;
    for (int k0 = 0; k0 < K; k0 += 32) {
        __syncthreads();
        *(uint4*)&As[lr][lc] = *(const uint4*)&A[(size_t)(m0 + lr) * lda + k0 + lc];
        *(uint4*)&Bs[lr][lc] = *(const uint4*)&Bt[(size_t)(n0 + lr) * ldb + k0 + lc];
        __syncthreads();
        bf16x8 a = *(const bf16x8*)&As[w * 16 + col][quad * 8];
#pragma unroll
        for (int nt = 0; nt < 4; ++nt) {
            bf16x8 bfr = *(const bf16x8*)&Bs[nt * 16 + col][quad * 8];
            acc[nt] = __builtin_amdgcn_mfma_f32_16x16x32_bf16(a, bfr, acc[nt], 0, 0, 0);
        }
    }
}

// Weff[j][d] = Whh[j][d] + sum_c Wih[j][c]*Wp[c][d]   (bf16 out)
__global__ void weff_kernel(const bf16* __restrict__ WihP, const bf16* __restrict__ WpTP,
                            const float* __restrict__ Whh, bf16* __restrict__ WeffP) {
    f32x4 acc[4] = {{0,0,0,0},{0,0,0,0},{0,0,0,0},{0,0,0,0}};
    int m0 = blockIdx.y * 64, n0 = blockIdx.x * 64;
    gemm_core_64x64(WihP, CP, WpTP, CP, CP, m0, n0, acc);
    int tid = threadIdx.x, w = tid >> 6, lane = tid & 63;
    int quad = lane >> 4, col = lane & 15;
#pragma unroll
    for (int nt = 0; nt < 4; ++nt)
#pragma unroll
        for (int r = 0; r < 4; ++r) {
            int j = m0 + w * 16 + quad * 4 + r;
            int d = n0 + nt * 16 + col;
            WeffP[j * DD + d] = __float2bfloat16(acc[nt][r] + Whh[j * DD + d]);
        }
}

// Final projection + denorm: out[b][t][c] = (Hd[t*BB+b,:]@Wp[c,:] + bp[c])*std + mean
__global__ void proj_kernel(const bf16* __restrict__ Hd, const bf16* __restrict__ WpP,
                            const float* __restrict__ bp, const float* __restrict__ stdp,
                            const float* __restrict__ meanp, float* __restrict__ out) {
    f32x4 acc[4] = {{0,0,0,0},{0,0,0,0},{0,0,0,0},{0,0,0,0}};
    int m0 = blockIdx.x * 64, n0 = blockIdx.y * 64;
    gemm_core_64x64(Hd, DD, WpP, DD, DD, m0, n0, acc);
    int tid = threadIdx.x, w = tid >> 6, lane = tid & 63;
    int quad = lane >> 4, col = lane & 15;
#pragma unroll
    for (int nt = 0; nt < 4; ++nt) {
        int c = n0 + nt * 16 + col;
        if (c >= CC) continue;
        float bpc = bp[c];
#pragma unroll
        for (int r = 0; r < 4; ++r) {
            int row = m0 + w * 16 + quad * 4 + r;   // = t*BB + b
            int t = row >> 8, b = row & 255;
            float y = acc[nt][r] + bpc;
            int sc = b * CC + c;
            out[(b * PP + t) * CC + c] = y * stdp[sc] + meanp[sc];
        }
    }
}

// ---------------------------------------------------------------------------
// Persistent recurrence kernel — R6 protocol, PLAIN h loads.
// (R7 was an infra failure — "container failed twice", no kernel signal —
// so this resubmits the R7 experiment unchanged to keep it isolated.)
//
// R6 post-mortem: three protocol styles (R0/R3/R6) all cost 6.2-7.2us/step;
// MfmaUtil cycle math shows the clock is ~2.4GHz, so the chain is ~16K REAL
// cycles. Unmodeled cost: h crossed as 16K agent-scope ATOMIC loads per step
// (512 waves x 32), hammering the MALL atomic path and inflating every trip.
// The h DATA needs no atomicity — only the flag does.
//
// ONE CHANGE vs R6: h-phase loads are PLAIN uint4 loads (16x16B/lane).
// Safety argument (why R4/R5's staleness cannot recur): every read of Hall
// row s-1 happens strictly AFTER the flag-wait proves all stores to that row
// committed at the MALL. No wave touches a row's lines pre-commit (no
// speculation/sentinel polling), kernel-launch boundaries invalidate L2s,
// and rows are write-once -> first post-flag access misses to MALL and
// caches the FINAL value; cached copies stay fresh forever. R4/R5 died by
// polling data PRE-commit (caching stale lines). The sched_barrier(0) after
// the poll is LOAD-BEARING: it stops the compiler hoisting the reorderable
// plain loads above the flag wait.
// Bonus: the 32 consumers of a b-tile slice sit on ONE XCD (role grouping),
// so the 32KB row-slice is MALL-fetched once and L2-served 31x (~200cy).
//
// Unchanged (proven): producer release = atomic h store -> vmcnt(0) -> lane0
// atomic flag store; consumer = relaxed atomic flag poll + s_sleep backoff;
// write-once Hall; XCD role grouping; lane-linear LDS weights; x-phase
// hoisted; Weff swap with barriers both sides.
// R1 lesson: epilogue stays tanhf + exact-division sigmoid.
__global__ __launch_bounds__(128, 1) void lstm_persistent(
        const bf16* __restrict__ xn,     // [TT*BB][CP]
        const bf16* __restrict__ WihP,   // [GG][CP]
        const bf16* __restrict__ WhhP,   // [GG][DD]
        const bf16* __restrict__ WeffP,  // [GG][DD]
        const float* __restrict__ bsum, const float* __restrict__ beff,
        bf16* __restrict__ Hall,         // [NSTEPS][BB][DD] write-once
        unsigned int* __restrict__ bar) {
    // lane-linear fragment LDS: frag(gt,ki) occupies 64 lanes x 16B contiguous
    __shared__ unsigned short Whs[4 * 16 * 64 * 8];   // 64 KB
    __shared__ unsigned short Wxs[4 * 11 * 64 * 8];   // 44 KB
    __shared__ int role_sh;

    const int tid = threadIdx.x;
    const int w = tid >> 6, lane = tid & 63;
    const int quad = lane >> 4, col = lane & 15;

    // ---- runtime XCD-local role assignment (proven R3/R6) ----
    unsigned int xcd;
    asm volatile("s_getreg_b32 %0, hwreg(HW_REG_XCC_ID)" : "=s"(xcd));
    xcd &= 7;
    if (tid == 0)
        role_sh = (int)__hip_atomic_fetch_add(&bar[xcd], 1u, __ATOMIC_RELAXED,
                                              __HIP_MEMORY_SCOPE_AGENT);
    __syncthreads();
    const int dt = role_sh & 31;             // d-tile within the XCD group
    const int bt = (int)xcd;                 // b-tile == XCD
    const int d0 = dt * 16;
    const int b0 = bt * 32;
    const int batch = b0 + w * 16 + col;     // this lane's batch (B-frag n)
    unsigned int* const flags = bar + 64 + bt * 64;  // 64 u32 per b-tile

    // ---- one-time weight staging (coalesced 16B reads, q fastest) ----
    for (int i = tid; i < 4096; i += 128) {          // Whh: 4gt x 16ki x 16row x 4q
        int q = i & 3, ki = (i >> 2) & 15, row = (i >> 6) & 15, gt = i >> 10;
        *(uint4*)&Whs[((gt * 16 + ki) * 64 + q * 16 + row) * 8] =
            *(const uint4*)&WhhP[(size_t)(gt * DD + d0 + row) * DD + ki * 32 + q * 8];
    }
    for (int i = tid; i < 2816; i += 128) {          // Wih: 4gt x 11ki x 16row x 4q
        int q = i & 3; int t = i >> 2; int ki = t % 11; t /= 11;
        int row = t & 15, gt = t >> 4;
        *(uint4*)&Wxs[((gt * 11 + ki) * 64 + q * 16 + row) * 8] =
            *(const uint4*)&WihP[(size_t)(gt * DD + d0 + row) * CP + ki * 32 + q * 8];
    }
    __syncthreads();

    // per-lane persistent state: c for (batch, d0+quad*4+r)
    float creg[4] = {0.f, 0.f, 0.f, 0.f};
    float bs_[16], be_[16];                  // [gate*4 + r], d = d0+quad*4+r
#pragma unroll
    for (int g4 = 0; g4 < 16; ++g4) {
        int gt = g4 >> 2, r = g4 & 3;
        bs_[g4] = bsum[gt * DD + d0 + quad * 4 + r];
        be_[g4] = beff[gt * DD + d0 + quad * 4 + r];
    }

    const size_t own_slot = (size_t)batch * DD + d0 + quad * 4;  // 4 bf16 (8B)
    // consumer's producers = wave w of the 32 d-tile blocks of this b-tile
    const int fidx = (lane & 31) * 2 + w;

    for (int s = 0; s < NSTEPS; ++s) {
        const bool enc = (s < TT);
        bf16* h_out = Hall + (size_t)s * HROT;

        f32x4 acc[4] = {{0,0,0,0},{0,0,0,0},{0,0,0,0},{0,0,0,0}};

        // x-phase BEFORE the wait: no dependence on h -> off the critical path
        if (enc) {
            uint4 xf[11];
            const uint4* xp = (const uint4*)(xn + (size_t)(s * BB + batch) * CP) + quad;
#pragma unroll
            for (int ki = 0; ki < 11; ++ki) xf[ki] = xp[ki * 4];
#pragma unroll
            for (int ki = 0; ki < 11; ++ki) {
                bf16x8 xv = *(bf16x8*)&xf[ki];
#pragma unroll
                for (int gt = 0; gt < 4; ++gt) {
                    bf16x8 wf = *(const bf16x8*)&Wxs[((gt * 11 + ki) * 64 + lane) * 8];
                    acc[gt] = __builtin_amdgcn_mfma_f32_16x16x32_bf16(wf, xv, acc[gt], 0, 0, 0);
                }
            }
        }

        // flag wait (R3/R6-proven): monotone flags, single writer each,
        // RELAXED AGENT -> MALL; s_sleep backoff.
        if (s > 0) {
            unsigned int tgt = (unsigned int)s;
            int guard = 0;
            while (__hip_atomic_load(&flags[fidx], __ATOMIC_RELAXED,
                                     __HIP_MEMORY_SCOPE_AGENT) < tgt) {
                __builtin_amdgcn_s_sleep(2);             // ~128cy backoff
                if (++guard >= (1 << 20)) break;         // fail, not hang
            }
            // LOAD-BEARING: plain h loads below must not be hoisted above
            // the flag wait by the compiler (relaxed atomics don't order
            // plain loads). sched_barrier(0) pins program order here.
            __builtin_amdgcn_sched_barrier(0);
        }

        // swap Whh -> Weff once at first decoder step; barrier on both sides
        // covers the sibling wave.
        if (s == TT) {
            __syncthreads();
            for (int i = tid; i < 4096; i += 128) {
                int q = i & 3, ki = (i >> 2) & 15, row = (i >> 6) & 15, gt = i >> 10;
                *(uint4*)&Whs[((gt * 16 + ki) * 64 + q * 16 + row) * 8] =
                    *(const uint4*)&WeffP[(size_t)(gt * DD + d0 + row) * DD + ki * 32 + q * 8];
            }
            __syncthreads();
        }

        // h-phase: PLAIN vectorized h loads (post-flag => committed; rows are
        // write-once => cached copies are final). 16x16B per lane, then
        // K=512 MFMA with conflict-free lane-linear weight reads.
        // s==0 skips entirely: h(-1)=0 contributes nothing.
        if (s > 0) {
            uint4 hq[16];
            const uint4* hp = (const uint4*)(Hall + (size_t)(s - 1) * HROT
                                             + (size_t)batch * DD) + quad;
#pragma unroll
            for (int ki = 0; ki < 16; ++ki) hq[ki] = hp[ki * 4];
#pragma unroll
            for (int ki = 0; ki < 16; ++ki) {
                bf16x8 hv = *(bf16x8*)&hq[ki];
#pragma unroll
                for (int gt = 0; gt < 4; ++gt) {
                    bf16x8 wf = *(const bf16x8*)&Whs[((gt * 16 + ki) * 64 + lane) * 8];
                    acc[gt] = __builtin_amdgcn_mfma_f32_16x16x32_bf16(wf, hv, acc[gt], 0, 0, 0);
                }
            }
        }

        // epilogue: gates [i,f,g,o]; lane owns d = d0+quad*4+(0..3) for `batch`
        // PRECISION-CRITICAL: keep tanhf + exact-division sigmoid (see header)
        u64 pack = 0;
#pragma unroll
        for (int r = 0; r < 4; ++r) {
            float iv = acc[0][r] + (enc ? bs_[0 + r] : be_[0 + r]);
            float fv = acc[1][r] + (enc ? bs_[4 + r] : be_[4 + r]);
            float gv = acc[2][r] + (enc ? bs_[8 + r] : be_[8 + r]);
            float ov = acc[3][r] + (enc ? bs_[12 + r] : be_[12 + r]);
            float si = 1.f / (1.f + __expf(-iv));
            float sf = 1.f / (1.f + __expf(-fv));
            float so = 1.f / (1.f + __expf(-ov));
            float tg = tanhf(gv);
            float cc = sf * creg[r] + si * tg;
            creg[r] = cc;
            float hvv = so * tanhf(cc);
            union { bf16 h; unsigned short u; } cv;
            cv.h = __float2bfloat16(hvv);
            pack |= (u64)cv.u << (16 * r);
        }
        // release (proven): atomic h store -> drain -> lane0 flag store
        __hip_atomic_store((u64*)&h_out[own_slot], pack,
                           __ATOMIC_RELAXED, __HIP_MEMORY_SCOPE_AGENT);
        asm volatile("s_waitcnt vmcnt(0)" ::: "memory");
        if (lane == 0)
            __hip_atomic_store(&flags[dt * 2 + w], (unsigned int)(s + 1),
                               __ATOMIC_RELAXED, __HIP_MEMORY_SCOPE_AGENT);
    }
}

// ---------------------------------------------------------------------------
extern "C" void kernel_launch(void* const* d_in, const int* in_sizes, int n_in,
                              void* d_out, int out_size, void* d_ws, size_t ws_size,
                              hipStream_t stream) {
    (void)in_sizes; (void)n_in; (void)out_size;
    const float* x_enc = (const float*)d_in[0];
    const float* Wih   = (const float*)d_in[1];
    const float* Whh   = (const float*)d_in[2];
    const float* bih   = (const float*)d_in[3];
    const float* bhh   = (const float*)d_in[4];
    const float* Wp    = (const float*)d_in[5];
    const float* bp    = (const float*)d_in[6];
    float* out = (float*)d_out;

    // workspace layout (all chunks 256B-aligned); R5/R6 proved ws >= 74.4MB
    char* ws = (char*)d_ws;
    size_t off = 0;
    float* meanp = (float*)(ws + off); off += (size_t)BB * CC * 4;
    float* stdp  = (float*)(ws + off); off += (size_t)BB * CC * 4;
    bf16* xnormP = (bf16*)(ws + off);  off += (size_t)TT * BB * CP * 2;
    bf16* WihP   = (bf16*)(ws + off);  off += (size_t)GG * CP * 2;
    bf16* WhhP   = (bf16*)(ws + off);  off += (size_t)GG * DD * 2;
    bf16* WeffP  = (bf16*)(ws + off);  off += (size_t)GG * DD * 2;
    bf16* WpTP   = (bf16*)(ws + off);  off += (size_t)DD * CP * 2;
    bf16* WpP    = (bf16*)(ws + off);  off += (size_t)384 * DD * 2;
    float* bsum  = (float*)(ws + off); off += (size_t)GG * 4;
    float* beff  = (float*)(ws + off); off += (size_t)GG * 4;
    bf16* Hall   = (bf16*)(ws + off);  off += (size_t)NSTEPS * HROT * 2;  // 47.8 MB
    unsigned int* bar = (unsigned int*)(ws + off); off += 4096;  // roles + flags
    if (ws_size < off) return;  // ~74.4 MB needed (proven available)

    // zero-init (ws is re-poisoned before every timed call)
    hipMemsetAsync(xnormP, 0, (size_t)TT * BB * CP * 2, stream);
    hipMemsetAsync(WihP,   0, (size_t)GG * CP * 2, stream);
    hipMemsetAsync(WpTP,   0, (size_t)DD * CP * 2, stream);
    hipMemsetAsync(WpP,    0, (size_t)384 * DD * 2, stream);
    hipMemsetAsync(bar,    0, 4096, stream);
    // Hall needs no init: every row is flag-guarded before any read

    norm_kernel<<<(BB * CC + 255) / 256, 256, 0, stream>>>(x_enc, meanp, stdp, xnormP);
    cast_pad_kernel<<<(GG * CC + 255) / 256, 256, 0, stream>>>(Wih, WihP, GG, CC, CP);
    cast_pad_kernel<<<(GG * DD + 255) / 256, 256, 0, stream>>>(Whh, WhhP, GG, DD, DD);
    cast_pad_kernel<<<(CC * DD + 255) / 256, 256, 0, stream>>>(Wp, WpP, CC, DD, DD);
    transpose_wp_kernel<<<(DD * CC + 255) / 256, 256, 0, stream>>>(Wp, WpTP);
    bias_kernel<<<GG / 256, 256, 0, stream>>>(Wih, bih, bhh, bp, bsum, beff);
    weff_kernel<<<dim3(DD / 64, GG / 64), 256, 0, stream>>>(WihP, WpTP, Whh, WeffP);

    // the whole 191-step recurrence in one cooperative launch
    const bf16* xn_c = xnormP;  const bf16* wih_c = WihP;
    const bf16* whh_c = WhhP;   const bf16* weff_c = WeffP;
    const float* bs_c = bsum;   const float* be_c = beff;
    bf16* ha_c = Hall; unsigned int* bar_c = bar;
    void* args[] = {&xn_c, &wih_c, &whh_c, &weff_c, &bs_c, &be_c,
                    &ha_c, &bar_c};
    hipLaunchCooperativeKernel((void*)lstm_persistent, dim3(256), dim3(128),
                               args, 0, stream);

    // ys[t] = proj(h(95+t)) -> rows 95..190 of Hall
    proj_kernel<<<dim3(PP * BB / 64, 384 / 64), 256, 0, stream>>>(
        Hall + 95 * HROT, WpP, bp, stdp, meanp, out);
}

// Round 9
// 1308.955 us; speedup vs baseline: 1.1170x; 1.1170x over previous
//
#include <hip/hip_runtime.h>
#include <hip/hip_bf16.h>
#include <math.h>

#define BB 256      // batch
#define TT 96       // seq len
#define PP 96       // pred len
#define CC 321      // enc_in
#define CP 352      // padded enc_in (11*32)
#define DD 512      // d_model
#define GG 2048     // 4*DD
#define NSTEPS 191  // 96 encoder + 95 decoder (decoder step 96 output is unused)
#define HROT ((size_t)BB * DD)   // elements per h row (one step)

typedef __attribute__((ext_vector_type(8))) short bf16x8;
typedef __attribute__((ext_vector_type(4))) float f32x4;
typedef __hip_bfloat16 bf16;
typedef unsigned long long u64;

// ---------------------------------------------------------------------------
// Instance norm over time: mean/stdev per (b,c); write normalized x to
// xnorm[t][b][c] (bf16, row pitch CP, pad cols pre-zeroed by memset).
__global__ void norm_kernel(const float* __restrict__ x, float* __restrict__ meanp,
                            float* __restrict__ stdp, bf16* __restrict__ xn) {
    int g = blockIdx.x * 256 + threadIdx.x;      // 0 .. BB*CC-1
    if (g >= BB * CC) return;
    int b = g / CC, c = g % CC;
    const float* xp = x + b * TT * CC + c;
    float s = 0.f;
    for (int t = 0; t < TT; ++t) s += xp[t * CC];
    float mu = s * (1.f / TT);
    float v = 0.f;
    for (int t = 0; t < TT; ++t) { float d0 = xp[t * CC] - mu; v += d0 * d0; }
    float sd = sqrtf(v * (1.f / TT) + 1e-5f);
    float rs = 1.f / sd;
    meanp[g] = mu;
    stdp[g] = sd;
    for (int t = 0; t < TT; ++t)
        xn[(t * BB + b) * CP + c] = __float2bfloat16((xp[t * CC] - mu) * rs);
}

// Cast fp32 [rows][cols] -> bf16 [rows][ldd] (pad cols pre-zeroed if ldd>cols)
__global__ void cast_pad_kernel(const float* __restrict__ src, bf16* __restrict__ dst,
                                int rows, int cols, int ldd) {
    int i = blockIdx.x * 256 + threadIdx.x;
    if (i >= rows * cols) return;
    int r = i / cols, c = i % cols;
    dst[r * ldd + c] = __float2bfloat16(src[i]);
}

// WpT[d][c] = Wp[c][d]  (bf16, row pitch CP, pad pre-zeroed)
__global__ void transpose_wp_kernel(const float* __restrict__ wp, bf16* __restrict__ wpt) {
    int i = blockIdx.x * 256 + threadIdx.x;      // over DD*CC
    if (i >= DD * CC) return;
    int d = i / CC, c = i % CC;
    wpt[d * CP + c] = __float2bfloat16(wp[c * DD + d]);
}

// bsum[j] = bih+bhh ; beff[j] = bih+bhh + dot(Wih[j,:], bp)   (fp32)
__global__ void bias_kernel(const float* __restrict__ Wih, const float* __restrict__ bih,
                            const float* __restrict__ bhh, const float* __restrict__ bp,
                            float* __restrict__ bsum, float* __restrict__ beff) {
    int j = blockIdx.x * 256 + threadIdx.x;      // 2048
    if (j >= GG) return;
    float s = bih[j] + bhh[j];
    float acc = 0.f;
    const float* w = Wih + j * CC;
    for (int c = 0; c < CC; ++c) acc += w[c] * bp[c];
    bsum[j] = s;
    beff[j] = s + acc;
}

// ---------------------------------------------------------------------------
// Generic 64x64 block MFMA core: C[m][n] = sum_k A[m][k] * Bt[n][k]
__device__ __forceinline__ void gemm_core_64x64(const bf16* A, int lda, const bf16* Bt,
                                                int ldb, int K, int m0, int n0,
                                                f32x4 acc[4]) {
    __shared__ unsigned short As[64][40];
    __shared__ unsigned short Bs[64][40];
    int tid = threadIdx.x;
    int w = tid >> 6, lane = tid & 63;
    int quad = lane >> 4, col = lane & 15;
    int lr = tid >> 2, lc = (tid & 3) * 8;
    for (int k0 = 0; k0 < K; k0 += 32) {
        __syncthreads();
        *(uint4*)&As[lr][lc] = *(const uint4*)&A[(size_t)(m0 + lr) * lda + k0 + lc];
        *(uint4*)&Bs[lr][lc] = *(const uint4*)&Bt[(size_t)(n0 + lr) * ldb + k0 + lc];
        __syncthreads();
        bf16x8 a = *(const bf16x8*)&As[w * 16 + col][quad * 8];
#pragma unroll
        for (int nt = 0; nt < 4; ++nt) {
            bf16x8 bfr = *(const bf16x8*)&Bs[nt * 16 + col][quad * 8];
            acc[nt] = __builtin_amdgcn_mfma_f32_16x16x32_bf16(a, bfr, acc[nt], 0, 0, 0);
        }
    }
}

// Weff[j][d] = Whh[j][d] + sum_c Wih[j][c]*Wp[c][d]   (bf16 out)
__global__ void weff_kernel(const bf16* __restrict__ WihP, const bf16* __restrict__ WpTP,
                            const float* __restrict__ Whh, bf16* __restrict__ WeffP) {
    f32x4 acc[4] = {{0,0,0,0},{0,0,0,0},{0,0,0,0},{0,0,0,0}};
    int m0 = blockIdx.y * 64, n0 = blockIdx.x * 64;
    gemm_core_64x64(WihP, CP, WpTP, CP, CP, m0, n0, acc);
    int tid = threadIdx.x, w = tid >> 6, lane = tid & 63;
    int quad = lane >> 4, col = lane & 15;
#pragma unroll
    for (int nt = 0; nt < 4; ++nt)
#pragma unroll
        for (int r = 0; r < 4; ++r) {
            int j = m0 + w * 16 + quad * 4 + r;
            int d = n0 + nt * 16 + col;
            WeffP[j * DD + d] = __float2bfloat16(acc[nt][r] + Whh[j * DD + d]);
        }
}

// ---------------------------------------------------------------------------
// Persistent recurrence kernel — R0 barrier protocol (fixed) + FUSED PROJ.
//
// Evidence across R0/R3/R6/R8: step time ~6.2-7.2us is invariant to protocol
// style; R0's single-poller barrier (tid0 fetch_add + s_sleep poll) is the
// FASTEST variant (1159-1192us vs 1261-1378 for all flag schemes) — 256
// pollers instead of 32K lane-polls; congestion is the secondary effect.
// This kernel: R0 protocol verbatim, EXCEPT the latent R0 bug where the
// xcd role counters aliased b-tile0's barrier counter (bar[0]) is fixed
// (counters moved to bar+256). Plain h loads kept (R8-proven: post-barrier
// first-touch of write-once rows cannot be stale).
//
// FUSED PROJ (new): during decoder step s, the wave has ALREADY loaded
// h(s-1) fragments (hq[]) for the recurrence — and h(s-1), rows 95..189,
// is exactly a proj input row. Each block dt<24 owns a 16-col slice of
// Wp (staged once into 16KB spare LDS, fragment-linear); after posting its
// barrier arrival (so nobody is delayed), it spends ~16 MFMAs + 4 stores
// inside the otherwise-idle poll window computing
//   out[b][t][c] = (h(s-1)[b,:]@Wp[c,:] + bp[c])*std + mean,  t = s-96.
// Row 190 (t=95) is projected after the final barrier. proj_kernel deleted.
//
// R1 lesson: epilogue stays tanhf + exact-division sigmoid.
__global__ __launch_bounds__(128, 1) void lstm_persistent(
        const bf16* __restrict__ xn,     // [TT*BB][CP]
        const bf16* __restrict__ WihP,   // [GG][CP]
        const bf16* __restrict__ WhhP,   // [GG][DD]
        const bf16* __restrict__ WeffP,  // [GG][DD]
        const float* __restrict__ bsum, const float* __restrict__ beff,
        bf16* __restrict__ Hall,         // [NSTEPS][BB][DD] write-once
        const bf16* __restrict__ WpP,    // [384][DD] (rows >=321 zero)
        const float* __restrict__ bp,
        const float* __restrict__ stdp, const float* __restrict__ meanp,
        float* __restrict__ out,         // [BB][PP][CC]
        unsigned int* __restrict__ bar) {
    // lane-linear fragment LDS: frag(gt,ki) occupies 64 lanes x 16B contiguous
    __shared__ unsigned short Whs[4 * 16 * 64 * 8];   // 64 KB
    __shared__ unsigned short Wxs[4 * 11 * 64 * 8];   // 44 KB
    __shared__ unsigned short PAs[16 * 64 * 8];       // 16 KB (proj Wp slice)
    __shared__ int role_sh;

    const int tid = threadIdx.x;
    const int w = tid >> 6, lane = tid & 63;
    const int quad = lane >> 4, col = lane & 15;

    // ---- runtime XCD-local role assignment (proven R3/R6/R8) ----
    unsigned int xcd;
    asm volatile("s_getreg_b32 %0, hwreg(HW_REG_XCC_ID)" : "=s"(xcd));
    xcd &= 7;
    if (tid == 0)
        role_sh = (int)__hip_atomic_fetch_add(&bar[xcd], 1u, __ATOMIC_RELAXED,
                                              __HIP_MEMORY_SCOPE_AGENT);
    __syncthreads();
    const int dt = role_sh & 31;             // d-tile within the XCD group
    const int bt = (int)xcd;                 // b-tile == XCD
    const int d0 = dt * 16;
    const int b0 = bt * 32;
    const int batch = b0 + w * 16 + col;     // this lane's batch (B-frag n)
    // barrier counter: bar+256 onward, 128B apart (NO aliasing with roles —
    // R0 had bar[0] doubly used as xcd0 role ctr AND btile0 barrier: latent race)
    unsigned int* const ctr = bar + 256 + bt * 32;

    // ---- one-time weight staging (coalesced 16B reads, q fastest) ----
    for (int i = tid; i < 4096; i += 128) {          // Whh: 4gt x 16ki x 16row x 4q
        int q = i & 3, ki = (i >> 2) & 15, row = (i >> 6) & 15, gt = i >> 10;
        *(uint4*)&Whs[((gt * 16 + ki) * 64 + q * 16 + row) * 8] =
            *(const uint4*)&WhhP[(size_t)(gt * DD + d0 + row) * DD + ki * 32 + q * 8];
    }
    for (int i = tid; i < 2816; i += 128) {          // Wih: 4gt x 11ki x 16row x 4q
        int q = i & 3; int t = i >> 2; int ki = t % 11; t /= 11;
        int row = t & 15, gt = t >> 4;
        *(uint4*)&Wxs[((gt * 11 + ki) * 64 + q * 16 + row) * 8] =
            *(const uint4*)&WihP[(size_t)(gt * DD + d0 + row) * CP + ki * 32 + q * 8];
    }
    // proj A-slice: 16 Wp rows (cols c0..c0+15) x K=512, fragment-linear
    const bool pact = (dt < 24);             // 24 blocks x 16 cols = 384
    const int c0 = dt * 16;
    if (pact) {
        for (int i = tid; i < 1024; i += 128) {      // 16ki x 16row x 4q
            int q = i & 3, ki = (i >> 2) & 15, row = (i >> 6) & 15;
            *(uint4*)&PAs[(ki * 64 + q * 16 + row) * 8] =
                *(const uint4*)&WpP[(size_t)(c0 + row) * DD + ki * 32 + q * 8];
        }
    }
    __syncthreads();

    // per-lane persistent state: c for (batch, d0+quad*4+r)
    float creg[4] = {0.f, 0.f, 0.f, 0.f};
    float bs_[16], be_[16];                  // [gate*4 + r], d = d0+quad*4+r
#pragma unroll
    for (int g4 = 0; g4 < 16; ++g4) {
        int gt = g4 >> 2, r = g4 & 3;
        bs_[g4] = bsum[gt * DD + d0 + quad * 4 + r];
        be_[g4] = beff[gt * DD + d0 + quad * 4 + r];
    }
    // per-lane proj constants: c = c0 + quad*4 + r for this lane's batch
    float pbp[4], pstd[4], pmean[4];
    bool pok[4];
#pragma unroll
    for (int r = 0; r < 4; ++r) {
        int c = c0 + quad * 4 + r;
        pok[r] = pact && (c < CC);
        pbp[r]   = pok[r] ? bp[c] : 0.f;
        pstd[r]  = pok[r] ? stdp[batch * CC + c] : 0.f;
        pmean[r] = pok[r] ? meanp[batch * CC + c] : 0.f;
    }

    const size_t own_slot = (size_t)batch * DD + d0 + quad * 4;  // 4 bf16 (8B)
    unsigned int gen = 0;

    for (int s = 0; s < NSTEPS; ++s) {
        const bool enc = (s < TT);
        bf16* h_out = Hall + (size_t)s * HROT;

        // swap Whh -> Weff at first decoder step. Previous step's trailing
        // __syncthreads guarantees both waves finished reading old Whs.
        if (s == TT) {
            for (int i = tid; i < 4096; i += 128) {
                int q = i & 3, ki = (i >> 2) & 15, row = (i >> 6) & 15, gt = i >> 10;
                *(uint4*)&Whs[((gt * 16 + ki) * 64 + q * 16 + row) * 8] =
                    *(const uint4*)&WeffP[(size_t)(gt * DD + d0 + row) * DD + ki * 32 + q * 8];
            }
            __syncthreads();
        }

        f32x4 acc[4] = {{0,0,0,0},{0,0,0,0},{0,0,0,0},{0,0,0,0}};

        // x-phase (encoder): static input, plain cached loads
        if (enc) {
            uint4 xf[11];
            const uint4* xp = (const uint4*)(xn + (size_t)(s * BB + batch) * CP) + quad;
#pragma unroll
            for (int ki = 0; ki < 11; ++ki) xf[ki] = xp[ki * 4];
#pragma unroll
            for (int ki = 0; ki < 11; ++ki) {
                bf16x8 xv = *(bf16x8*)&xf[ki];
#pragma unroll
                for (int gt = 0; gt < 4; ++gt) {
                    bf16x8 wf = *(const bf16x8*)&Wxs[((gt * 11 + ki) * 64 + lane) * 8];
                    acc[gt] = __builtin_amdgcn_mfma_f32_16x16x32_bf16(wf, xv, acc[gt], 0, 0, 0);
                }
            }
        }

        // h-phase: PLAIN vectorized loads of h(s-1) (post-barrier first-touch
        // of a write-once row — R8-proven fresh), then K=512 MFMA.
        // s==0 skips: h(-1)=0 contributes nothing. hq[] stays live for proj.
        uint4 hq[16];
        if (s > 0) {
            const uint4* hp = (const uint4*)(Hall + (size_t)(s - 1) * HROT
                                             + (size_t)batch * DD) + quad;
#pragma unroll
            for (int ki = 0; ki < 16; ++ki) hq[ki] = hp[ki * 4];
#pragma unroll
            for (int ki = 0; ki < 16; ++ki) {
                bf16x8 hv = *(bf16x8*)&hq[ki];
#pragma unroll
                for (int gt = 0; gt < 4; ++gt) {
                    bf16x8 wf = *(const bf16x8*)&Whs[((gt * 16 + ki) * 64 + lane) * 8];
                    acc[gt] = __builtin_amdgcn_mfma_f32_16x16x32_bf16(wf, hv, acc[gt], 0, 0, 0);
                }
            }
        }

        // epilogue: gates [i,f,g,o]; lane owns d = d0+quad*4+(0..3) for `batch`
        // PRECISION-CRITICAL: keep tanhf + exact-division sigmoid (see header)
        u64 pack = 0;
#pragma unroll
        for (int r = 0; r < 4; ++r) {
            float iv = acc[0][r] + (enc ? bs_[0 + r] : be_[0 + r]);
            float fv = acc[1][r] + (enc ? bs_[4 + r] : be_[4 + r]);
            float gv = acc[2][r] + (enc ? bs_[8 + r] : be_[8 + r]);
            float ov = acc[3][r] + (enc ? bs_[12 + r] : be_[12 + r]);
            float si = 1.f / (1.f + __expf(-iv));
            float sf = 1.f / (1.f + __expf(-fv));
            float so = 1.f / (1.f + __expf(-ov));
            float tg = tanhf(gv);
            float cc = sf * creg[r] + si * tg;
            creg[r] = cc;
            float hvv = so * tanhf(cc);
            union { bf16 h; unsigned short u; } cv;
            cv.h = __float2bfloat16(hvv);
            pack |= (u64)cv.u << (16 * r);
        }
        __hip_atomic_store((u64*)&h_out[own_slot], pack,
                           __ATOMIC_RELAXED, __HIP_MEMORY_SCOPE_AGENT);
        asm volatile("s_waitcnt vmcnt(0)" ::: "memory");   // store at MALL
        __syncthreads();                                    // both waves drained
        ++gen;
        if (tid == 0)
            __hip_atomic_fetch_add(ctr, 1u, __ATOMIC_RELAXED,
                                   __HIP_MEMORY_SCOPE_AGENT);

        // ---- FUSED PROJ filler (decoder): arrival already posted, so this
        // delays nobody; it fills our own otherwise-idle poll window.
        // Reuses hq[] = h(s-1) = Hdec row (s-TT) as B-operands.
        if (pact && s >= TT) {
            f32x4 pacc = {0.f, 0.f, 0.f, 0.f};
#pragma unroll
            for (int ki = 0; ki < 16; ++ki) {
                bf16x8 pa = *(const bf16x8*)&PAs[(ki * 64 + lane) * 8];
                bf16x8 hv = *(bf16x8*)&hq[ki];
                pacc = __builtin_amdgcn_mfma_f32_16x16x32_bf16(pa, hv, pacc, 0, 0, 0);
            }
            int t = s - TT;                  // 0..94
#pragma unroll
            for (int r = 0; r < 4; ++r)
                if (pok[r])
                    out[((size_t)batch * PP + t) * CC + c0 + quad * 4 + r] =
                        (pacc[r] + pbp[r]) * pstd[r] + pmean[r];
        }

        // barrier release: single poller per block (R0-proven fastest)
        if (tid == 0) {
            unsigned int tgt = gen * 32u;
            int guard = 0;
            while (__hip_atomic_load(ctr, __ATOMIC_RELAXED,
                                     __HIP_MEMORY_SCOPE_AGENT) < tgt) {
                __builtin_amdgcn_s_sleep(1);
                if (++guard >= (1 << 20)) break;   // fail, not hang
            }
        }
        __syncthreads();
    }

    // tail: proj the last decoder row (Hall row 190, t=95). Final barrier
    // above proved all of row 190 is committed.
    if (pact) {
        uint4 hq[16];
        const uint4* hp = (const uint4*)(Hall + (size_t)(NSTEPS - 1) * HROT
                                         + (size_t)batch * DD) + quad;
#pragma unroll
        for (int ki = 0; ki < 16; ++ki) hq[ki] = hp[ki * 4];
        f32x4 pacc = {0.f, 0.f, 0.f, 0.f};
#pragma unroll
        for (int ki = 0; ki < 16; ++ki) {
            bf16x8 pa = *(const bf16x8*)&PAs[(ki * 64 + lane) * 8];
            bf16x8 hv = *(bf16x8*)&hq[ki];
            pacc = __builtin_amdgcn_mfma_f32_16x16x32_bf16(pa, hv, pacc, 0, 0, 0);
        }
#pragma unroll
        for (int r = 0; r < 4; ++r)
            if (pok[r])
                out[((size_t)batch * PP + (PP - 1)) * CC + c0 + quad * 4 + r] =
                    (pacc[r] + pbp[r]) * pstd[r] + pmean[r];
    }
}

// ---------------------------------------------------------------------------
extern "C" void kernel_launch(void* const* d_in, const int* in_sizes, int n_in,
                              void* d_out, int out_size, void* d_ws, size_t ws_size,
                              hipStream_t stream) {
    (void)in_sizes; (void)n_in; (void)out_size;
    const float* x_enc = (const float*)d_in[0];
    const float* Wih   = (const float*)d_in[1];
    const float* Whh   = (const float*)d_in[2];
    const float* bih   = (const float*)d_in[3];
    const float* bhh   = (const float*)d_in[4];
    const float* Wp    = (const float*)d_in[5];
    const float* bp    = (const float*)d_in[6];
    float* out = (float*)d_out;

    // workspace layout (all chunks 256B-aligned); R5/R6/R8 proved ws >= 74.4MB
    char* ws = (char*)d_ws;
    size_t off = 0;
    float* meanp = (float*)(ws + off); off += (size_t)BB * CC * 4;
    float* stdp  = (float*)(ws + off); off += (size_t)BB * CC * 4;
    bf16* xnormP = (bf16*)(ws + off);  off += (size_t)TT * BB * CP * 2;
    bf16* WihP   = (bf16*)(ws + off);  off += (size_t)GG * CP * 2;
    bf16* WhhP   = (bf16*)(ws + off);  off += (size_t)GG * DD * 2;
    bf16* WeffP  = (bf16*)(ws + off);  off += (size_t)GG * DD * 2;
    bf16* WpTP   = (bf16*)(ws + off);  off += (size_t)DD * CP * 2;
    bf16* WpP    = (bf16*)(ws + off);  off += (size_t)384 * DD * 2;
    float* bsum  = (float*)(ws + off); off += (size_t)GG * 4;
    float* beff  = (float*)(ws + off); off += (size_t)GG * 4;
    bf16* Hall   = (bf16*)(ws + off);  off += (size_t)NSTEPS * HROT * 2;  // 47.8 MB
    unsigned int* bar = (unsigned int*)(ws + off); off += 4096;  // roles + ctrs
    if (ws_size < off) return;  // ~74.4 MB needed (proven available)

    // zero-init (ws is re-poisoned before every timed call)
    hipMemsetAsync(xnormP, 0, (size_t)TT * BB * CP * 2, stream);
    hipMemsetAsync(WihP,   0, (size_t)GG * CP * 2, stream);
    hipMemsetAsync(WpTP,   0, (size_t)DD * CP * 2, stream);
    hipMemsetAsync(WpP,    0, (size_t)384 * DD * 2, stream);
    hipMemsetAsync(bar,    0, 4096, stream);
    // Hall needs no init: every row is barrier-guarded before any read

    norm_kernel<<<(BB * CC + 255) / 256, 256, 0, stream>>>(x_enc, meanp, stdp, xnormP);
    cast_pad_kernel<<<(GG * CC + 255) / 256, 256, 0, stream>>>(Wih, WihP, GG, CC, CP);
    cast_pad_kernel<<<(GG * DD + 255) / 256, 256, 0, stream>>>(Whh, WhhP, GG, DD, DD);
    cast_pad_kernel<<<(CC * DD + 255) / 256, 256, 0, stream>>>(Wp, WpP, CC, DD, DD);
    transpose_wp_kernel<<<(DD * CC + 255) / 256, 256, 0, stream>>>(Wp, WpTP);
    bias_kernel<<<GG / 256, 256, 0, stream>>>(Wih, bih, bhh, bp, bsum, beff);
    weff_kernel<<<dim3(DD / 64, GG / 64), 256, 0, stream>>>(WihP, WpTP, Whh, WeffP);

    // the whole 191-step recurrence + fused projection in one cooperative launch
    const bf16* xn_c = xnormP;  const bf16* wih_c = WihP;
    const bf16* whh_c = WhhP;   const bf16* weff_c = WeffP;
    const float* bs_c = bsum;   const float* be_c = beff;
    bf16* ha_c = Hall;          const bf16* wp_c = WpP;
    const float* bp_c = bp;     const float* sd_c = stdp;
    const float* mn_c = meanp;  float* out_c = out;
    unsigned int* bar_c = bar;
    void* args[] = {&xn_c, &wih_c, &whh_c, &weff_c, &bs_c, &be_c,
                    &ha_c, &wp_c, &bp_c, &sd_c, &mn_c, &out_c, &bar_c};
    hipLaunchCooperativeKernel((void*)lstm_persistent, dim3(256), dim3(128),
                               args, 0, stream);
}